// Round 1
// baseline (137.461 us; speedup 1.0000x reference)
//
#include <hip/hip_runtime.h>
#include <stdint.h>

#define HW 9216
#define CDIM 128
#define WIDTH 96
#define BATCH 2
#define SPLITS 4            // 4 key-splits x 4 wk-waves = 16 partial streams (ws layout unchanged)
#define KSPLIT 2304         // keys per split
#define NTILE 18            // 2304 / 128 keys per LDS tile

// Logits are computed as w = dot * QSCALE with e = (e^w)^2 = exp(dot/(0.1*sqrt(128))).
// Folding ln2/2 into the Q scale makes w directly the argument of the packed
// poly-exp (|dot|<=1 for unit vectors -> |w| <= 0.4420, well inside the
// Taylor-4 domain; rel err ~3e-4, below the existing f16 quantization noise).
#define QSCALE 0.44194173824159216f
// conf numerator: exp(2*mx) = exp2(mx * 2/ln2)
#define MXSCALE 2.8853900817779268f

typedef _Float16 half8 __attribute__((ext_vector_type(8)));
typedef float f32x16 __attribute__((ext_vector_type(16)));
typedef float float4v __attribute__((ext_vector_type(4)));
typedef float float2v __attribute__((ext_vector_type(2)));

// ---------------------------------------------------------------------------
// Kernel 1: L2-normalize over C, write fp16 [B][HW][C]. Tiled: block = 64
// positions x 128 channels, values kept in registers, output staged through
// padded LDS so global stores are fully coalesced 16B/lane.
// ---------------------------------------------------------------------------
__global__ __launch_bounds__(256) void norm_kernel(const float* __restrict__ fL,
                                                   const float* __restrict__ fR,
                                                   _Float16* __restrict__ Qh,
                                                   _Float16* __restrict__ Kh)
{
    __shared__ float ssred[4][64];
    __shared__ _Float16 ot[64 * 130];   // +2 halves pad -> bank advance 1/row

    const float* src = (blockIdx.y == 0) ? fL : fR;
    _Float16* dst    = (blockIdx.y == 0) ? Qh : Kh;
    const float outScale = (blockIdx.y == 0) ? QSCALE : 1.0f;

    const int t = threadIdx.x;
    const int pos_l = t & 63, cg = t >> 6;            // 4 channel groups of 32
    const int pos0 = blockIdx.x * 64;                  // 64 | HW so no straddle
    const int b = pos0 / HW, pos_in = pos0 % HW + pos_l;

    const float* p = src + (size_t)b * CDIM * HW + pos_in;

    float v[32];
    float ss = 0.f;
    #pragma unroll
    for (int j = 0; j < 32; ++j) {
        v[j] = p[(size_t)(cg * 32 + j) * HW];
        ss += v[j] * v[j];
    }
    ssred[cg][pos_l] = ss;
    __syncthreads();
    float tot = ssred[0][pos_l] + ssred[1][pos_l] + ssred[2][pos_l] + ssred[3][pos_l];
    float scale = outScale / fmaxf(sqrtf(tot), 1e-6f);

    #pragma unroll
    for (int j = 0; j < 32; ++j)
        ot[pos_l * 130 + cg * 32 + j] = (_Float16)(v[j] * scale);
    __syncthreads();

    // coalesced write-out: 16 KB tile, 4 x uint4 per thread
    uint4* og = (uint4*)(dst + (size_t)(b * HW + pos0 % HW + 0) * CDIM);
    #pragma unroll
    for (int i = 0; i < 4; ++i) {
        int idx = i * 256 + t;            // 0..1023 dwordx4 slots
        int row = idx >> 4, chunk = idx & 15;
        og[idx] = *(const uint4*)&ot[row * 130 + chunk * 8];
    }
}

// ---------------------------------------------------------------------------
// Kernel 2: fused correlation + softmax-accumulate, restructured.
//   Block: 512 threads = 8 waves as 2(wq) x 4(wk) over a 64q x 128k tile.
//   MFMA: swapped 32x32x16 f16 -> D rows = keys (crow(reg)+4*hi), cols = q
//   (lane&31). 8 MFMA per tile-wave (vs 16 of 16x16x32) at the better 32x32
//   rate; per-lane softmax state collapses to one q-column.
//   exp: packed deg-4 Taylor + square (no quarter-rate v_exp_f32 in the loop).
//   Coordinates: within each wave's 32-key window, key%96 never wraps
//   (base = 32*((4t+wk)%3) <= 64, crow+4hi <= 31), so
//     x = b_tile + crow + 4hi  (b_tile: period-3 table),
//     y = split*24 + (4t+wk)/3 (tile-constant!).
//   => per tile: E2[p] += e (crow weights applied ONCE at the end with
//   compile-time constants), axb += lt*b, ay += lt*y. ~134 VALU-cy/tile-wave
//   vs 228 before.
//   LDS: 2 x 32KB double buffer, XOR-chunk swizzle, global_load_lds width-16,
//   one barrier per 128-key tile (half the barrier events per key), 2 blocks
//   x 8 waves = 16 waves/CU for cross-block overlap.
// ---------------------------------------------------------------------------
__global__ __launch_bounds__(512, 4) void attn_kernel(const _Float16* __restrict__ Qh,
                                                      const _Float16* __restrict__ Kh,
                                                      float4* __restrict__ part)
{
    __shared__ __align__(16) _Float16 Ks[2 * 128 * 128];   // 2 x 32 KB

    const int qt = blockIdx.x, split = blockIdx.y, b = blockIdx.z;
    const int t = threadIdx.x;
    const int lane = t & 63, wave = t >> 6;        // 8 waves
    const int wq = wave >> 2, wk = wave & 3;       // 2 (q) x 4 (k)
    const int lane31 = lane & 31, hi = lane >> 5;
    const int ln15 = lane & 15, qd = lane >> 4;

    const char* kp0 = (const char*)(Kh + (size_t)b * HW * CDIM) +
                      (size_t)(split * KSPLIT) * (CDIM * 2);

    // staging voffsets: wave stages rows [wave*16, wave*16+16). LDS dest is
    // linear (instr adds lane*16B); source 16B-chunk XOR-swizzled so
    // LDS[r][c] = K[r][c ^ (r&15)] -> conflict-free fragment reads.
    int voff[4];
    #pragma unroll
    for (int i = 0; i < 4; ++i) {
        int r = wave * 16 + i * 4 + qd;
        voff[i] = r * 256 + ((ln15 ^ (r & 15)) << 4);
    }

    #define STAGE(TILE, BUF)                                                     \
        {                                                                        \
            const char* kb_ = kp0 + (size_t)(TILE) * 32768;                      \
            _Float16* db_ = &Ks[(BUF) * 16384 + wave * (16 * 128)];              \
            _Pragma("unroll")                                                    \
            for (int i_ = 0; i_ < 4; ++i_)                                       \
                __builtin_amdgcn_global_load_lds(                                \
                    (const __attribute__((address_space(1))) uint32_t*)(kb_ + voff[i_]), \
                    (__attribute__((address_space(3))) uint32_t*)(db_ + i_ * (4 * 128)), \
                    16, 0, 0);                                                   \
        }

    STAGE(0, 0);   // start DMA before the register prologue

    // ---- Q fragments (B-operand of swapped MFMA): col = lane31 = q-row ----
    // B layout 32x32x16: lane holds col=lane&31, k = hi*8 + j  ->  per kc
    // (16-ch chunk) read 16B at ch = kc*16 + hi*8.
    half8 qf[8];
    {
        const char* qb = (const char*)(Qh +
            ((size_t)(b * HW + qt * 64 + wq * 32 + lane31)) * CDIM);
        #pragma unroll
        for (int kc = 0; kc < 8; ++kc)
            qf[kc] = *(const half8*)(qb + kc * 32 + hi * 16);
    }

    // ---- K-frag (A-operand) LDS read offsets: row = key = wk*32 + lane31,
    // global 16B-chunk (kc*2+hi), un-swizzled via ^ln15. Banks: chunk spans
    // all 16 values across lanes -> minimum 8 bank-cycles per b128, 0 conflict.
    int rdoff[8];
    #pragma unroll
    for (int kc = 0; kc < 8; ++kc)
        rdoff[kc] = ((wk * 32 + lane31) << 8) + ((((kc << 1) | hi) ^ ln15) << 4);

    // ---- period-3 coordinate tables ----
    // key = split*2304 + kt*128 + wk*32 + crow + 4hi ; (kt*128+wk*32)%96 =
    // 32*((kt+wk)%3) in {0,32,64}; + (crow+4hi)<=31 -> <=95, never wraps.
    float2v xb2[3], yw2[3];
    #pragma unroll
    for (int p = 0; p < 3; ++p) {
        xb2[p] = (float2v)(float)(32 * ((p + wk) % 3));
        yw2[p] = (float2v)(float)(split * 24 + (4 * p + wk) / 3);
    }

    float2v E2[8];                       // per reg-pair e-sums (crow applied at end)
    #pragma unroll
    for (int p = 0; p < 8; ++p) E2[p] = (float2v)0.f;
    float2v mx2 = (float2v)(-1.0e30f);
    float2v axb2 = (float2v)0.f, ay2 = (float2v)0.f;

    const char* ksb = (const char*)&Ks[0];
    const float2v C4 = (float2v)(1.0f / 24.0f), C3 = (float2v)(1.0f / 6.0f),
                  C2 = (float2v)0.5f, C1 = (float2v)1.0f;

    __syncthreads();

    #pragma unroll
    for (int kt = 0; kt < NTILE; ++kt) {
        const int cur = kt & 1;                    // compile-time
        const int ph = kt % 3;                     // compile-time
        const float yadd = (float)(4 * (kt / 3));  // compile-time literal

        if (kt < NTILE - 1) STAGE(kt + 1, 1 - cur);   // covered by MFMA+epilogue

        f32x16 acc;
        __builtin_amdgcn_s_setprio(1);
        #pragma unroll
        for (int kc = 0; kc < 8; ++kc) {
            half8 kf = *(const half8*)(ksb + cur * 32768 + rdoff[kc]);
            acc = __builtin_amdgcn_mfma_f32_32x32x16_f16(
                kf, qf[kc], (kc == 0) ? (f32x16)0.f : acc, 0, 0, 0);
        }
        __builtin_amdgcn_s_setprio(0);

        // ---- epilogue: packed poly-exp + slot accumulate ----
        // pairs (2p,2p+1) = consecutive key rows crow, crow+1
        float2v lt2;
        #pragma unroll
        for (int p = 0; p < 8; ++p) {
            float2v w;
            w.x = acc[2 * p];
            w.y = acc[2 * p + 1];
            mx2 = __builtin_elementwise_max(mx2, w);
            float2v h = w * C4 + C3;          // e^w, Taylor-4 on |w|<=0.444
            h = h * w + C2;
            h = h * w + C1;
            h = h * w + C1;
            float2v e = h * h;                // square back to full range
            E2[p] += e;
            lt2 = (p == 0) ? e : (lt2 + e);
        }
        axb2 += lt2 * xb2[ph];                     // x base part (tile-const)
        ay2  += lt2 * (yw2[ph] + (float2v)yadd);   // y fully tile-const
        __syncthreads();   // readers of cur done + prefetch drained
    }

    // ---- per-lane fold: apply compile-time crow weights once ----
    float l = 0.f, axc = 0.f;
    #pragma unroll
    for (int p = 0; p < 8; ++p) {
        const float c0 = (float)(((2 * p) & 3) + 8 * ((2 * p) >> 2)); // 0,2,8,10,16,18,24,26
        l   += E2[p].x + E2[p].y;
        axc += c0 * E2[p].x + (c0 + 1.0f) * E2[p].y;
    }
    float ax = axc + (float)(4 * hi) * l + axb2.x + axb2.y;
    float ay = ay2.x + ay2.y;
    float mx = fmaxf(mx2.x, mx2.y);

    // combine hi/lo key-halves (lanes l and l+32 share q = lane31)
    l  += __shfl_xor(l, 32, 64);
    ax += __shfl_xor(ax, 32, 64);
    ay += __shfl_xor(ay, 32, 64);
    mx  = fmaxf(mx, __shfl_xor(mx, 32, 64));

    if (hi == 0) {
        int row = qt * 64 + wq * 32 + lane31;
        part[(size_t)(split * 4 + wk) * (BATCH * HW) + b * HW + row] =
            make_float4(l, ax, ay, __builtin_amdgcn_exp2f(mx * MXSCALE));
    }
    #undef STAGE
}

// ---------------------------------------------------------------------------
// Kernel 3: combine 16 partials per query row, write flow + conf
// ---------------------------------------------------------------------------
__global__ __launch_bounds__(256) void combine_kernel(const float4* __restrict__ part,
                                                      float* __restrict__ out)
{
    int tid = blockIdx.x * 256 + threadIdx.x;   // 0 .. B*HW-1 (grid sized exactly)
    int b = tid / HW, pos = tid % HW;
    float l = 0.f, ax = 0.f, ay = 0.f, mx = 0.f;
    #pragma unroll
    for (int s = 0; s < 16; ++s) {
        float4 v = part[(size_t)s * (BATCH * HW) + tid];   // coalesced
        l += v.x; ax += v.y; ay += v.z; mx = fmaxf(mx, v.w);
    }
    float inv = 1.0f / l;
    int x = pos % WIDTH, y = pos / WIDTH;
    out[(size_t)b * 2 * HW + pos]           = ax * inv - (float)x;
    out[(size_t)b * 2 * HW + HW + pos]      = ay * inv - (float)y;
    out[(size_t)BATCH * 2 * HW + (size_t)b * HW + pos] = mx * inv;
}

// ---------------------------------------------------------------------------
extern "C" void kernel_launch(void* const* d_in, const int* in_sizes, int n_in,
                              void* d_out, int out_size, void* d_ws, size_t ws_size,
                              hipStream_t stream)
{
    const float* fL = (const float*)d_in[0];
    const float* fR = (const float*)d_in[1];
    float* out = (float*)d_out;

    char* ws = (char*)d_ws;
    const size_t QH_BYTES = (size_t)BATCH * HW * CDIM * sizeof(_Float16);  // 4.72 MB
    _Float16* Qh  = (_Float16*)ws;
    _Float16* Kh  = (_Float16*)(ws + QH_BYTES);
    float4*   part = (float4*)(ws + 2 * QH_BYTES);                         // 4.72 MB

    norm_kernel<<<dim3((BATCH * HW) / 64, 2), 256, 0, stream>>>(fL, fR, Qh, Kh);
    attn_kernel<<<dim3(HW / 64, SPLITS, BATCH), 512, 0, stream>>>(Qh, Kh, part);
    combine_kernel<<<dim3((BATCH * HW) / 256), 256, 0, stream>>>(part, out);
}